// Round 6
// baseline (1899.390 us; speedup 1.0000x reference)
//
#include <hip/hip_runtime.h>
#include <cstddef>

constexpr int NB = 256;
constexpr int NT = 512;
constexpr int NV = 32;

__device__ __forceinline__ float sigmoidf_(float x){ return 1.0f/(1.0f+__expf(-x)); }
__device__ __forceinline__ float tanhf_(float x){ return 1.0f - 2.0f/(__expf(2.0f*x)+1.0f); }
__device__ __forceinline__ float hsum4_(const float4 a){ return (a.x+a.y)+(a.z+a.w); }

// Pin a float4's components into VGPRs (un-rematerializable defs).
#define PIN4(v4_) asm volatile("" : "+v"((v4_).x), "+v"((v4_).y), "+v"((v4_).z), "+v"((v4_).w))
#define SBAR() __builtin_amdgcn_sched_barrier(0)

// ---------------- stats + x_comp ----------------
__global__ __launch_bounds__(256) void k_stats(
    const float* __restrict__ values, const float* __restrict__ masks,
    const int* __restrict__ lengths,
    float* __restrict__ x_comp, float* __restrict__ stats)
{
  const int b = blockIdx.x;
  const int v = threadIdx.x & 31;
  const int g = threadIdx.x >> 5;
  const int len = lengths[b];
  const float* vb = values + (size_t)b*NT*NV;
  const float* mb = masks  + (size_t)b*NT*NV;
  float* xb = x_comp + (size_t)b*NT*NV;
  float s_m=0.f, s_mv=0.f, s_v=0.f, s_v2=0.f;
  for (int t=g; t<NT; t+=8){
    float val = vb[t*NV+v];
    float m   = mb[t*NV+v];
    float xp  = (t==0) ? vb[v] : vb[(t-1)*NV+v];
    float pm  = (t<len) ? 1.0f : 0.0f;
    xb[t*NV+v] = (m*val + (1.0f-m)*xp)*pm;
    s_m += m; s_mv += m*val; s_v += val; s_v2 += val*val;
  }
  __shared__ float red[4][8][32];
  red[0][g][v]=s_m; red[1][g][v]=s_mv; red[2][g][v]=s_v; red[3][g][v]=s_v2;
  __syncthreads();
  if (g==0){
    float a0=0,a1=0,a2=0,a3=0;
    #pragma unroll
    for(int i=0;i<8;i++){ a0+=red[0][i][v]; a1+=red[1][i][v]; a2+=red[2][i][v]; a3+=red[3][i][v]; }
    float msum = fmaxf(a0, 1.0f);
    float mean = a1/msum;
    float dss  = a3 - 2.0f*mean*a2 + (float)NT*mean*mean;
    float var  = (msum > 1.0f) ? dss/(msum-1.0f) : 0.0f;
    float sd   = sqrtf(fmaxf(var, 0.0f));
    float miss = 1.0f - a0 / fmaxf((float)len, 1.0f);
    float* st = stats + b*97;
    if (v==0) st[0] = (float)len;
    st[1+v]=mean; st[33+v]=sd; st[65+v]=miss;
  }
}

// ---------------- context MLP ----------------
__global__ __launch_bounds__(64) void k_cmlp(
    const float* __restrict__ stats,
    const float* __restrict__ W1, const float* __restrict__ b1,
    const float* __restrict__ W2, const float* __restrict__ b2,
    float* __restrict__ ctx)
{
  const int b = blockIdx.x;
  const int j = threadIdx.x;
  __shared__ float st[97];
  __shared__ float hm[64];
  for (int k=j; k<97; k+=64) st[k] = stats[b*97+k];
  __syncthreads();
  float a0=b1[j], a1=0.f, a2=0.f, a3=0.f;
  #pragma unroll
  for (int k=0; k<96; k+=4){
    a0 += st[k]*W1[j*97+k];     a1 += st[k+1]*W1[j*97+k+1];
    a2 += st[k+2]*W1[j*97+k+2]; a3 += st[k+3]*W1[j*97+k+3];
  }
  a0 += st[96]*W1[j*97+96];
  hm[j] = fmaxf((a0+a1)+(a2+a3), 0.0f);
  __syncthreads();
  if (j < 32){
    float c0_=b2[j], c1=0.f, c2=0.f, c3=0.f;
    #pragma unroll
    for (int k=0;k<64;k+=4){
      c0_ += hm[k]*W2[j*64+k];    c1 += hm[k+1]*W2[j*64+k+1];
      c2 += hm[k+2]*W2[j*64+k+2]; c3 += hm[k+3]*W2[j*64+k+3];
    }
    ctx[b*64+j] = (c0_+c1)+(c2+c3);
  }
}

// ---------------- GRU scan: 128 threads, full 128-wide dot per thread ----------------
__global__ __launch_bounds__(128,2) void k_gru(
    const float* __restrict__ x_comp, const float* __restrict__ rain_f,
    const float* __restrict__ rain_bw, const int* __restrict__ lengths,
    const float* __restrict__ Wih, const float* __restrict__ Whh,
    const float* __restrict__ bih, const float* __restrict__ bhh,
    float* __restrict__ ctx)
{
  const int b = blockIdx.x;
  const int tid = threadIdx.x;
  const int j = tid;
  const bool act = (j < 96);
  int len = lengths[b]; if (len > NT) len = NT;
  const float4 FZ4 = {0.f,0.f,0.f,0.f};
  const float4* WI4 = (const float4*)(Wih + (size_t)(act ? j : 0)*96);
  const float4* WH4 = (const float4*)(Whh + (size_t)(act ? j : 0)*32);
  float4 wi0 = act?WI4[0]:FZ4,  wi1 = act?WI4[1]:FZ4,  wi2 = act?WI4[2]:FZ4,  wi3 = act?WI4[3]:FZ4;
  float4 wi4 = act?WI4[4]:FZ4,  wi5 = act?WI4[5]:FZ4,  wi6 = act?WI4[6]:FZ4,  wi7 = act?WI4[7]:FZ4;
  float4 wi8 = act?WI4[8]:FZ4,  wi9 = act?WI4[9]:FZ4,  wi10= act?WI4[10]:FZ4, wi11= act?WI4[11]:FZ4;
  float4 wi12= act?WI4[12]:FZ4, wi13= act?WI4[13]:FZ4, wi14= act?WI4[14]:FZ4, wi15= act?WI4[15]:FZ4;
  float4 wi16= act?WI4[16]:FZ4, wi17= act?WI4[17]:FZ4, wi18= act?WI4[18]:FZ4, wi19= act?WI4[19]:FZ4;
  float4 wi20= act?WI4[20]:FZ4, wi21= act?WI4[21]:FZ4, wi22= act?WI4[22]:FZ4, wi23= act?WI4[23]:FZ4;
  float4 wh0 = act?WH4[0]:FZ4,  wh1 = act?WH4[1]:FZ4,  wh2 = act?WH4[2]:FZ4,  wh3 = act?WH4[3]:FZ4;
  float4 wh4 = act?WH4[4]:FZ4,  wh5 = act?WH4[5]:FZ4,  wh6 = act?WH4[6]:FZ4,  wh7 = act?WH4[7]:FZ4;
  PIN4(wi0); PIN4(wi1); PIN4(wi2); PIN4(wi3); PIN4(wi4); PIN4(wi5); PIN4(wi6); PIN4(wi7);
  PIN4(wi8); PIN4(wi9); PIN4(wi10); PIN4(wi11); PIN4(wi12); PIN4(wi13); PIN4(wi14); PIN4(wi15);
  PIN4(wi16); PIN4(wi17); PIN4(wi18); PIN4(wi19); PIN4(wi20); PIN4(wi21); PIN4(wi22); PIN4(wi23);
  PIN4(wh0); PIN4(wh1); PIN4(wh2); PIN4(wh3); PIN4(wh4); PIN4(wh5); PIN4(wh6); PIN4(wh7);
  const float bi = act ? bih[j] : 0.f;
  const float bh = act ? bhh[j] : 0.f;
  __shared__ __align__(16) float h_lds[32];
  __shared__ __align__(16) float xrow[2][96];
  __shared__ float gi_lds[96];
  __shared__ float gh_lds[96];
  const float* xc = x_comp + (size_t)b*NT*NV;
  const float* rf = rain_f + (size_t)b*NT*NV;
  const float* rb = rain_bw + (size_t)b*NT*NV;
  if (tid < 32) h_lds[tid] = 0.0f;
  if (tid >= 32){
    const int jj = tid - 32;
    xrow[0][jj] = (jj<32) ? xc[jj] : (jj<64 ? rf[jj-32] : rb[jj-64]);
  }
  __syncthreads();
  for (int t=0; t<len; ++t){
    const int cur = t & 1;
    float pf = 0.f;
    const bool dopf = (tid >= 32) && (t+1 < len);
    if (dopf){
      const int jj = tid - 32, tn = t+1;
      pf = (jj<32) ? xc[tn*NV+jj] : (jj<64 ? rf[tn*NV+jj-32] : rb[tn*NV+jj-64]);
    }
    {
      const float* u = &xrow[cur][0];
      float4 ai = {bi, 0.f, 0.f, 0.f};
      #define GSTEP(i, wn) { const float4 uv = *(const float4*)(u + 4*(i)); \
        ai.x = fmaf(uv.x, wn.x, ai.x); ai.y = fmaf(uv.y, wn.y, ai.y); \
        ai.z = fmaf(uv.z, wn.z, ai.z); ai.w = fmaf(uv.w, wn.w, ai.w); }
      GSTEP(0,wi0) GSTEP(1,wi1) GSTEP(2,wi2) GSTEP(3,wi3)
      GSTEP(4,wi4) GSTEP(5,wi5) GSTEP(6,wi6) GSTEP(7,wi7)
      SBAR();
      GSTEP(8,wi8) GSTEP(9,wi9) GSTEP(10,wi10) GSTEP(11,wi11)
      GSTEP(12,wi12) GSTEP(13,wi13) GSTEP(14,wi14) GSTEP(15,wi15)
      SBAR();
      GSTEP(16,wi16) GSTEP(17,wi17) GSTEP(18,wi18) GSTEP(19,wi19)
      GSTEP(20,wi20) GSTEP(21,wi21) GSTEP(22,wi22) GSTEP(23,wi23)
      SBAR();
      float4 ah = {bh, 0.f, 0.f, 0.f};
      const float* hh = &h_lds[0];
      #define HSTEP(i, wn) { const float4 uv = *(const float4*)(hh + 4*(i)); \
        ah.x = fmaf(uv.x, wn.x, ah.x); ah.y = fmaf(uv.y, wn.y, ah.y); \
        ah.z = fmaf(uv.z, wn.z, ah.z); ah.w = fmaf(uv.w, wn.w, ah.w); }
      HSTEP(0,wh0) HSTEP(1,wh1) HSTEP(2,wh2) HSTEP(3,wh3)
      HSTEP(4,wh4) HSTEP(5,wh5) HSTEP(6,wh6) HSTEP(7,wh7)
      SBAR();
      #undef GSTEP
      #undef HSTEP
      if (act){ gi_lds[j] = hsum4_(ai); gh_lds[j] = hsum4_(ah); }
    }
    if (dopf) xrow[cur^1][tid-32] = pf;
    __syncthreads();
    if (tid < 32){
      const float r = sigmoidf_(gi_lds[tid] + gh_lds[tid]);
      const float z = sigmoidf_(gi_lds[32+tid] + gh_lds[32+tid]);
      const float n = tanhf_(gi_lds[64+tid] + r*gh_lds[64+tid]);
      h_lds[tid] = (1.0f - z)*n + z*h_lds[tid];
    }
    __syncthreads();
  }
  if (tid < 32) ctx[b*64 + 32 + tid] = h_lds[tid];
}

// ---------------- init: h0/c0, ctx-part of LSTM gates, hidden seeds ----------------
__global__ __launch_bounds__(256) void k_init(
    const float* __restrict__ ctx,
    const float* __restrict__ initW, const float* __restrict__ initb,
    const float* __restrict__ WihF, const float* __restrict__ bihF, const float* __restrict__ bhhF,
    const float* __restrict__ WihB, const float* __restrict__ bihB, const float* __restrict__ bhhB,
    float* __restrict__ h0, float* __restrict__ c0,
    float* __restrict__ cgF, float* __restrict__ cgB,
    float* __restrict__ hidden)
{
  const int b = blockIdx.x;
  const int j = threadIdx.x;
  __shared__ __align__(16) float cv[64];
  if (j < 64) cv[j] = ctx[b*64+j];
  __syncthreads();
  {
    float4 f = {bihF[j]+bhhF[j], 0.f, 0.f, 0.f};
    float4 g = {bihB[j]+bhhB[j], 0.f, 0.f, 0.f};
    #pragma unroll
    for (int q=0;q<16;q++){
      const float4 cvv = *(const float4*)&cv[4*q];
      const float4 wf = *(const float4*)(WihF + (size_t)j*128 + 64 + 4*q);
      const float4 wb = *(const float4*)(WihB + (size_t)j*128 + 64 + 4*q);
      f.x += cvv.x*wf.x; f.y += cvv.y*wf.y; f.z += cvv.z*wf.z; f.w += cvv.w*wf.w;
      g.x += cvv.x*wb.x; g.y += cvv.y*wb.y; g.z += cvv.z*wb.z; g.w += cvv.w*wb.w;
    }
    cgF[b*256+j] = hsum4_(f);
    cgB[b*256+j] = hsum4_(g);
  }
  if (j < 128){
    float4 a = {initb[j], 0.f, 0.f, 0.f};
    #pragma unroll
    for (int q=0;q<16;q++){
      const float4 cvv = *(const float4*)&cv[4*q];
      const float4 w  = *(const float4*)(initW + (size_t)j*64 + 4*q);
      a.x += cvv.x*w.x; a.y += cvv.y*w.y; a.z += cvv.z*w.z; a.w += cvv.w*w.w;
    }
    float hv = hsum4_(a);
    h0[b*128+j] = hv;
    c0[b*128+j] = tanhf_(hv);
    if (j < 64) hidden[(size_t)b*NT*128 + j] = hv;                                // fwd seed t=0
    else        hidden[(size_t)b*NT*128 + (size_t)(NT-1)*128 + 64 + (j-64)] = hv; // bwd seed t=T-1
  }
}

// ---------------- LSTM scans: 256 threads, full 128-wide dot per thread ----------------
__global__ __launch_bounds__(256,2) void k_lstm(
    const float* __restrict__ x_comp, const float* __restrict__ masks,
    const float* __restrict__ WihF, const float* __restrict__ WhhF,
    const float* __restrict__ WihB, const float* __restrict__ WhhB,
    const float* __restrict__ cgF, const float* __restrict__ cgB,
    const float* __restrict__ h0, const float* __restrict__ c0,
    const int* __restrict__ lengths,
    float* __restrict__ hidden)
{
  const int b = blockIdx.x;
  const int dir = blockIdx.y;
  const int tid = threadIdx.x;
  const int j = tid;
  const float* Wih = dir ? WihB : WihF;
  const float* Whh = dir ? WhhB : WhhF;
  const float4* WX4 = (const float4*)(Wih + (size_t)j*128);   // cols 0..63 (x,mask)
  const float4* WH4 = (const float4*)(Whh + (size_t)j*64);
  float4 x0 = WX4[0],  x1 = WX4[1],  x2 = WX4[2],  x3 = WX4[3];
  float4 x4 = WX4[4],  x5 = WX4[5],  x6 = WX4[6],  x7 = WX4[7];
  float4 x8 = WX4[8],  x9 = WX4[9],  x10 = WX4[10], x11 = WX4[11];
  float4 x12 = WX4[12], x13 = WX4[13], x14 = WX4[14], x15 = WX4[15];
  float4 h0w = WH4[0],  h1w = WH4[1],  h2w = WH4[2],  h3w = WH4[3];
  float4 h4w = WH4[4],  h5w = WH4[5],  h6w = WH4[6],  h7w = WH4[7];
  float4 h8w = WH4[8],  h9w = WH4[9],  h10w = WH4[10], h11w = WH4[11];
  float4 h12w = WH4[12], h13w = WH4[13], h14w = WH4[14], h15w = WH4[15];
  PIN4(x0); PIN4(x1); PIN4(x2); PIN4(x3); PIN4(x4); PIN4(x5); PIN4(x6); PIN4(x7);
  PIN4(x8); PIN4(x9); PIN4(x10); PIN4(x11); PIN4(x12); PIN4(x13); PIN4(x14); PIN4(x15);
  PIN4(h0w); PIN4(h1w); PIN4(h2w); PIN4(h3w); PIN4(h4w); PIN4(h5w); PIN4(h6w); PIN4(h7w);
  PIN4(h8w); PIN4(h9w); PIN4(h10w); PIN4(h11w); PIN4(h12w); PIN4(h13w); PIN4(h14w); PIN4(h15w);
  const float cg0 = (dir ? cgB : cgF)[b*256 + j];
  __shared__ __align__(16) float h_lds[64];
  __shared__ __align__(16) float xm[2][64];
  __shared__ float g_lds[256];
  float c = 0.0f;
  if (tid < 64){
    h_lds[tid] = h0[b*128 + dir*64 + tid];
    c          = c0[b*128 + dir*64 + tid];
  }
  const int len = lengths[b];
  int nsteps = NT-1;
  if (dir == 0){
    int e = len - 1; if (e < 0) e = 0;
    if (e < nsteps) nsteps = e;   // outputs past len are zeroed by padding mask
  }
  const float* xc = x_comp + (size_t)b*NT*NV;
  const float* mk = masks  + (size_t)b*NT*NV;
  float* hout = hidden + (size_t)b*NT*128 + dir*64;
  const int t0 = dir ? NT-1 : 0;
  if (tid >= 192){
    const int jj = tid - 192;
    xm[0][jj] = (jj<32) ? xc[t0*NV+jj] : mk[t0*NV+jj-32];
  }
  __syncthreads();
  for (int s=0; s<nsteps; ++s){
    const int cur = s & 1;
    float pf = 0.f;
    const bool dopf = (tid >= 192) && (s+1 < nsteps);
    if (dopf){
      const int jj = tid - 192;
      const int tn = dir ? (NT-2-s) : (s+1);
      pf = (jj<32) ? xc[tn*NV+jj] : mk[tn*NV+jj-32];
    }
    float4 acc = {cg0, 0.f, 0.f, 0.f};
    {
      const float* u = &xm[cur][0];
      #define LSTEP(i, wn) { const float4 uv = *(const float4*)(u + 4*(i)); \
        acc.x = fmaf(uv.x, wn.x, acc.x); acc.y = fmaf(uv.y, wn.y, acc.y); \
        acc.z = fmaf(uv.z, wn.z, acc.z); acc.w = fmaf(uv.w, wn.w, acc.w); }
      LSTEP(0,x0) LSTEP(1,x1) LSTEP(2,x2) LSTEP(3,x3)
      LSTEP(4,x4) LSTEP(5,x5) LSTEP(6,x6) LSTEP(7,x7)
      SBAR();
      LSTEP(8,x8) LSTEP(9,x9) LSTEP(10,x10) LSTEP(11,x11)
      LSTEP(12,x12) LSTEP(13,x13) LSTEP(14,x14) LSTEP(15,x15)
      SBAR();
      #undef LSTEP
      const float* hh = &h_lds[0];
      #define HSTEP(i, wn) { const float4 uv = *(const float4*)(hh + 4*(i)); \
        acc.x = fmaf(uv.x, wn.x, acc.x); acc.y = fmaf(uv.y, wn.y, acc.y); \
        acc.z = fmaf(uv.z, wn.z, acc.z); acc.w = fmaf(uv.w, wn.w, acc.w); }
      HSTEP(0,h0w) HSTEP(1,h1w) HSTEP(2,h2w) HSTEP(3,h3w)
      HSTEP(4,h4w) HSTEP(5,h5w) HSTEP(6,h6w) HSTEP(7,h7w)
      SBAR();
      HSTEP(8,h8w) HSTEP(9,h9w) HSTEP(10,h10w) HSTEP(11,h11w)
      HSTEP(12,h12w) HSTEP(13,h13w) HSTEP(14,h14w) HSTEP(15,h15w)
      SBAR();
      #undef HSTEP
    }
    g_lds[j] = hsum4_(acc);
    if (dopf) xm[cur^1][tid-192] = pf;
    __syncthreads();
    if (tid < 64){
      const float gi = g_lds[tid];
      const float gf = g_lds[64+tid];
      const float gg = g_lds[128+tid];
      const float go = g_lds[192+tid];
      c = sigmoidf_(gf)*c + sigmoidf_(gi)*tanhf_(gg);
      const float hh = sigmoidf_(go)*tanhf_(c);
      h_lds[tid] = hh;
      const int t    = dir ? (NT-1-s) : s;
      const int outt = dir ? (t-1)    : (s+1);
      hout[(size_t)outt*128 + tid] = hh;
    }
    __syncthreads();
  }
}

// ---------------- feature-regression path: 512 threads, 2 output rows per thread ----------------
__global__ __launch_bounds__(512,4) void k_feat(
    const float* __restrict__ x_comp,
    const float* __restrict__ feat_W, const float* __restrict__ feat_b,
    const float* __restrict__ nl1_W, const float* __restrict__ nl1_b,
    const float* __restrict__ nl2_W, const float* __restrict__ nl2_b,
    float* __restrict__ feat_imp)
{
  const int tid = threadIdx.x;
  const int lane = tid & 31;   // h-index (pass1), g-index (pass2)
  const int ig = tid >> 5;     // 0..15
  const int i0 = ig, i1 = ig + 16;
  const float4* A4 = (const float4*)(feat_W + ((size_t)(i0*32)+lane)*32);
  const float4* B4 = (const float4*)(feat_W + ((size_t)(i1*32)+lane)*32);
  #define LOADW(nm, P4, ii, cc) float4 nm = P4[cc]; \
    if (cc == ((ii)>>2)){ const int sub=(ii)&3; \
      if (sub==0) nm.x=0.f; else if (sub==1) nm.y=0.f; else if (sub==2) nm.z=0.f; else nm.w=0.f; } \
    PIN4(nm);
  LOADW(a0,A4,i0,0) LOADW(a1,A4,i0,1) LOADW(a2,A4,i0,2) LOADW(a3,A4,i0,3)
  LOADW(a4,A4,i0,4) LOADW(a5,A4,i0,5) LOADW(a6,A4,i0,6) LOADW(a7,A4,i0,7)
  LOADW(b0,B4,i1,0) LOADW(b1,B4,i1,1) LOADW(b2,B4,i1,2) LOADW(b3,B4,i1,3)
  LOADW(b4,B4,i1,4) LOADW(b5,B4,i1,5) LOADW(b6,B4,i1,6) LOADW(b7,B4,i1,7)
  #undef LOADW
  const float fb0 = feat_b[i0*32 + lane];
  const float fb1 = feat_b[i1*32 + lane];
  const float n1b = nl1_b[lane];
  const float n2w = nl2_W[lane];
  const float n2b = nl2_b[0];
  __shared__ __align__(16) float hid[32][36];
  __shared__ __align__(16) float nl1s[32][36];
  if (tid < 256){
    const int rrow = tid >> 3, c4 = (tid & 7) * 4;
    *(float4*)&nl1s[rrow][c4] = *(const float4*)(nl1_W + rrow*32 + c4);
  }
  __syncthreads();
  const int NP = NB*NT;
  for (int r = blockIdx.x; r < NP; r += gridDim.x){
    const float* xp = x_comp + (size_t)r*32;
    float4 acc0 = {fb0, 0.f, 0.f, 0.f};
    float4 acc1 = {fb1, 0.f, 0.f, 0.f};
    #define FST(i, an, bn) { const float4 xv = *(const float4*)(xp + 4*i); \
      acc0.x = fmaf(xv.x, an.x, acc0.x); acc0.y = fmaf(xv.y, an.y, acc0.y); \
      acc0.z = fmaf(xv.z, an.z, acc0.z); acc0.w = fmaf(xv.w, an.w, acc0.w); \
      acc1.x = fmaf(xv.x, bn.x, acc1.x); acc1.y = fmaf(xv.y, bn.y, acc1.y); \
      acc1.z = fmaf(xv.z, bn.z, acc1.z); acc1.w = fmaf(xv.w, bn.w, acc1.w); }
    FST(0,a0,b0) FST(1,a1,b1) FST(2,a2,b2) FST(3,a3,b3)
    SBAR();
    FST(4,a4,b4) FST(5,a5,b5) FST(6,a6,b6) FST(7,a7,b7)
    SBAR();
    #undef FST
    hid[i0][lane] = fmaxf(hsum4_(acc0), 0.0f);
    hid[i1][lane] = fmaxf(hsum4_(acc1), 0.0f);
    __syncthreads();
    float z0 = n1b, z1 = n1b;
    #pragma unroll
    for (int cc=0; cc<8; cc++){
      const float4 nn = *(const float4*)&nl1s[lane][4*cc];
      const float4 v0 = *(const float4*)&hid[i0][4*cc];
      const float4 v1 = *(const float4*)&hid[i1][4*cc];
      z0 += v0.x*nn.x + v0.y*nn.y + v0.z*nn.z + v0.w*nn.w;
      z1 += v1.x*nn.x + v1.y*nn.y + v1.z*nn.z + v1.w*nn.w;
      SBAR();
    }
    float cr0 = fmaxf(z0, 0.f)*n2w;
    float cr1 = fmaxf(z1, 0.f)*n2w;
    #pragma unroll
    for (int off=16; off>0; off>>=1){
      cr0 += __shfl_xor(cr0, off, 32);
      cr1 += __shfl_xor(cr1, off, 32);
    }
    if (lane == 0){
      feat_imp[(size_t)r*32 + i0] = cr0 + n2b;
      feat_imp[(size_t)r*32 + i1] = cr1 + n2b;
    }
    __syncthreads();
  }
}

// ---------------- rnn_imp GEMM + fuse + final: 512 threads, half-split of 128-dot ----------------
__global__ __launch_bounds__(512,4) void k_final(
    const float* __restrict__ values, const float* __restrict__ masks,
    const float* __restrict__ feat_imp, const float* __restrict__ hidden,
    const float* __restrict__ rimp_W, const float* __restrict__ rimp_b,
    const float* __restrict__ fuse_W, const float* __restrict__ fuse_b,
    const int* __restrict__ lengths, float* __restrict__ out)
{
  const int tid = threadIdx.x;
  const int v = tid & 31;
  const int grp = (tid >> 5) & 7;
  const int half = tid >> 8;
  const float4 FZ4 = {0.f,0.f,0.f,0.f};
  const float4* W4 = (const float4*)(rimp_W + (size_t)v*128 + half*64);
  float4 w0 = W4[0],  w1 = W4[1],  w2 = W4[2],  w3 = W4[3];
  float4 w4 = W4[4],  w5 = W4[5],  w6 = W4[6],  w7 = W4[7];
  float4 w8 = W4[8],  w9 = W4[9],  w10 = W4[10], w11 = W4[11];
  float4 w12 = W4[12], w13 = W4[13], w14 = W4[14], w15 = W4[15];
  PIN4(w0); PIN4(w1); PIN4(w2); PIN4(w3); PIN4(w4); PIN4(w5); PIN4(w6); PIN4(w7);
  PIN4(w8); PIN4(w9); PIN4(w10); PIN4(w11); PIN4(w12); PIN4(w13); PIN4(w14); PIN4(w15);
  const float4* F4 = (const float4*)(fuse_W + (size_t)v*64 + 32);
  float fconst = 0.f;
  if (!half){
    fconst = fuse_b[v];
    #pragma unroll
    for (int q=0;q<8;q++) fconst += hsum4_(*(const float4*)(fuse_W + (size_t)v*64 + 4*q)); // gamma==1 part
  }
  const float rbias = rimp_b[v];
  __shared__ __align__(16) float hrow[8][128];
  __shared__ float rpart[8][32];
  __shared__ float bpart[8][32];
  const int NOCT = (NB*NT)/8;
  for (int oc = blockIdx.x; oc < NOCT; oc += gridDim.x){
    const size_t base = (size_t)oc*8;
    __syncthreads();
    if (tid < 256) ((float4*)hrow)[tid] = ((const float4*)(hidden + base*128))[tid];
    __syncthreads();
    const size_t r = base + grp;
    float4 a = {half ? 0.f : rbias, 0.f, 0.f, 0.f};
    const float* hb = &hrow[grp][half*64];
    #define RST(i) { const float4 hv = *(const float4*)(hb + 4*i); \
      a.x = fmaf(hv.x, w##i.x, a.x); a.y = fmaf(hv.y, w##i.y, a.y); \
      a.z = fmaf(hv.z, w##i.z, a.z); a.w = fmaf(hv.w, w##i.w, a.w); }
    RST(0) RST(1) RST(2) RST(3)
    SBAR();
    RST(4) RST(5) RST(6) RST(7)
    SBAR();
    RST(8) RST(9) RST(10) RST(11)
    SBAR();
    RST(12) RST(13) RST(14) RST(15)
    SBAR();
    #undef RST
    if (half){
      rpart[grp][v] = hsum4_(a);
      const float* mrow = masks + r*32;
      float4 acc4 = FZ4;
      #pragma unroll
      for (int q=0;q<8;q++){
        const float4 mv = *(const float4*)(mrow + 4*q);
        const float4 fv = F4[q];
        acc4.x = fmaf(mv.x, fv.x, acc4.x); acc4.y = fmaf(mv.y, fv.y, acc4.y);
        acc4.z = fmaf(mv.z, fv.z, acc4.z); acc4.w = fmaf(mv.w, fv.w, acc4.w);
        SBAR();
      }
      bpart[grp][v] = hsum4_(acc4);
    }
    __syncthreads();
    if (!half){
      const int bb = (int)(r >> 9);   // T = 512
      const int t = (int)(r & 511);
      const int len = lengths[bb];
      const float rimp = hsum4_(a) + rpart[grp][v];
      const float beta = sigmoidf_(fconst + bpart[grp][v]);
      const float fi = feat_imp[r*32+v];
      const float m  = masks[r*32+v];
      const float val= values[r*32+v];
      const float fz = beta*fi + (1.0f-beta)*rimp;
      const float o = m*val + (1.0f-m)*fz;
      out[r*32+v] = (t < len) ? o : 0.0f;
    }
  }
}

extern "C" void kernel_launch(void* const* d_in, const int* in_sizes, int n_in,
                              void* d_out, int out_size, void* d_ws, size_t ws_size,
                              hipStream_t stream) {
  const float* values   = (const float*)d_in[0];
  const float* masks    = (const float*)d_in[1];
  const float* rain_f   = (const float*)d_in[2];
  const float* rain_b   = (const float*)d_in[3];
  const float* cmlp_W1  = (const float*)d_in[4];
  const float* cmlp_b1  = (const float*)d_in[5];
  const float* cmlp_W2  = (const float*)d_in[6];
  const float* cmlp_b2  = (const float*)d_in[7];
  const float* gru_Wih  = (const float*)d_in[8];
  const float* gru_Whh  = (const float*)d_in[9];
  const float* gru_bih  = (const float*)d_in[10];
  const float* gru_bhh  = (const float*)d_in[11];
  const float* init_W   = (const float*)d_in[12];
  const float* init_b   = (const float*)d_in[13];
  const float* lstmf_Wih= (const float*)d_in[14];
  const float* lstmf_Whh= (const float*)d_in[15];
  const float* lstmf_bih= (const float*)d_in[16];
  const float* lstmf_bhh= (const float*)d_in[17];
  const float* lstmb_Wih= (const float*)d_in[18];
  const float* lstmb_Whh= (const float*)d_in[19];
  const float* lstmb_bih= (const float*)d_in[20];
  const float* lstmb_bhh= (const float*)d_in[21];
  const float* rimp_W   = (const float*)d_in[22];
  const float* rimp_b   = (const float*)d_in[23];
  const float* feat_W   = (const float*)d_in[24];
  const float* feat_b   = (const float*)d_in[25];
  const float* nl1_W    = (const float*)d_in[26];
  const float* nl1_b    = (const float*)d_in[27];
  const float* nl2_W    = (const float*)d_in[28];
  const float* nl2_b    = (const float*)d_in[29];
  const float* fuse_W   = (const float*)d_in[30];
  const float* fuse_b   = (const float*)d_in[31];
  const int*   lengths  = (const int*)d_in[32];
  float* out = (float*)d_out;

  float* ws       = (float*)d_ws;
  float* x_comp   = ws;                                   // B*T*V
  float* stats    = x_comp + (size_t)NB*NT*NV;            // B*97
  float* ctx      = stats + NB*97;                        // B*64
  float* h0       = ctx + NB*64;                          // B*128
  float* c0      = h0 + NB*128;                           // B*128
  float* cgF      = c0 + NB*128;                          // B*256
  float* cgB      = cgF + NB*256;                         // B*256
  float* hidden   = cgB + NB*256;                         // B*T*128
  float* feat_imp = hidden + (size_t)NB*NT*128;           // B*T*V
  // total ~25.4M floats ~= 102 MB

  k_stats<<<NB, 256, 0, stream>>>(values, masks, lengths, x_comp, stats);
  k_feat<<<2048, 512, 0, stream>>>(x_comp, feat_W, feat_b, nl1_W, nl1_b, nl2_W, nl2_b, feat_imp);
  k_cmlp<<<NB, 64, 0, stream>>>(stats, cmlp_W1, cmlp_b1, cmlp_W2, cmlp_b2, ctx);
  k_gru<<<NB, 128, 0, stream>>>(x_comp, rain_f, rain_b, lengths, gru_Wih, gru_Whh, gru_bih, gru_bhh, ctx);
  k_init<<<NB, 256, 0, stream>>>(ctx, init_W, init_b,
                                 lstmf_Wih, lstmf_bih, lstmf_bhh,
                                 lstmb_Wih, lstmb_bih, lstmb_bhh,
                                 h0, c0, cgF, cgB, hidden);
  dim3 lgrid(NB, 2);
  k_lstm<<<lgrid, 256, 0, stream>>>(x_comp, masks,
                                    lstmf_Wih, lstmf_Whh, lstmb_Wih, lstmb_Whh,
                                    cgF, cgB, h0, c0, lengths, hidden);
  k_final<<<2048, 512, 0, stream>>>(values, masks, feat_imp, hidden,
                                    rimp_W, rimp_b, fuse_W, fuse_b, lengths, out);
}

// Round 7
// 1444.374 us; speedup vs baseline: 1.3150x; 1.3150x over previous
//
#include <hip/hip_runtime.h>
#include <cstddef>

constexpr int NB = 256;
constexpr int NT = 512;
constexpr int NV = 32;

typedef _Float16 h2_t __attribute__((ext_vector_type(2)));

__device__ __forceinline__ float sigmoidf_(float x){ return 1.0f/(1.0f+__expf(-x)); }
__device__ __forceinline__ float tanhf_(float x){ return 1.0f - 2.0f/(__expf(2.0f*x)+1.0f); }
__device__ __forceinline__ float hsum4_(const float4 a){ return (a.x+a.y)+(a.z+a.w); }

__device__ __forceinline__ float pack2_(float a, float b){
  h2_t r; r.x = (_Float16)a; r.y = (_Float16)b;
  return __builtin_bit_cast(float, r);
}
__device__ __forceinline__ float dot2f_(float u, float w, float c){
#if __has_builtin(__builtin_amdgcn_fdot2)
  return __builtin_amdgcn_fdot2(__builtin_bit_cast(h2_t,u), __builtin_bit_cast(h2_t,w), c, false);
#else
  h2_t a = __builtin_bit_cast(h2_t,u), b = __builtin_bit_cast(h2_t,w);
  return c + (float)a.x*(float)b.x + (float)a.y*(float)b.y;
#endif
}

// Pin values into VGPRs (un-rematerializable defs).
#define PIN4(v4_) asm volatile("" : "+v"((v4_).x), "+v"((v4_).y), "+v"((v4_).z), "+v"((v4_).w))
#define PINF(f_)  asm volatile("" : "+v"(f_))

// ---------------- stats + x_comp ----------------
__global__ __launch_bounds__(256) void k_stats(
    const float* __restrict__ values, const float* __restrict__ masks,
    const int* __restrict__ lengths,
    float* __restrict__ x_comp, float* __restrict__ stats)
{
  const int b = blockIdx.x;
  const int v = threadIdx.x & 31;
  const int g = threadIdx.x >> 5;
  const int len = lengths[b];
  const float* vb = values + (size_t)b*NT*NV;
  const float* mb = masks  + (size_t)b*NT*NV;
  float* xb = x_comp + (size_t)b*NT*NV;
  float s_m=0.f, s_mv=0.f, s_v=0.f, s_v2=0.f;
  for (int t=g; t<NT; t+=8){
    float val = vb[t*NV+v];
    float m   = mb[t*NV+v];
    float xp  = (t==0) ? vb[v] : vb[(t-1)*NV+v];
    float pm  = (t<len) ? 1.0f : 0.0f;
    xb[t*NV+v] = (m*val + (1.0f-m)*xp)*pm;
    s_m += m; s_mv += m*val; s_v += val; s_v2 += val*val;
  }
  __shared__ float red[4][8][32];
  red[0][g][v]=s_m; red[1][g][v]=s_mv; red[2][g][v]=s_v; red[3][g][v]=s_v2;
  __syncthreads();
  if (g==0){
    float a0=0,a1=0,a2=0,a3=0;
    #pragma unroll
    for(int i=0;i<8;i++){ a0+=red[0][i][v]; a1+=red[1][i][v]; a2+=red[2][i][v]; a3+=red[3][i][v]; }
    float msum = fmaxf(a0, 1.0f);
    float mean = a1/msum;
    float dss  = a3 - 2.0f*mean*a2 + (float)NT*mean*mean;
    float var  = (msum > 1.0f) ? dss/(msum-1.0f) : 0.0f;
    float sd   = sqrtf(fmaxf(var, 0.0f));
    float miss = 1.0f - a0 / fmaxf((float)len, 1.0f);
    float* st = stats + b*97;
    if (v==0) st[0] = (float)len;
    st[1+v]=mean; st[33+v]=sd; st[65+v]=miss;
  }
}

// ---------------- context MLP ----------------
__global__ __launch_bounds__(64) void k_cmlp(
    const float* __restrict__ stats,
    const float* __restrict__ W1, const float* __restrict__ b1,
    const float* __restrict__ W2, const float* __restrict__ b2,
    float* __restrict__ ctx)
{
  const int b = blockIdx.x;
  const int j = threadIdx.x;
  __shared__ float st[97];
  __shared__ float hm[64];
  for (int k=j; k<97; k+=64) st[k] = stats[b*97+k];
  __syncthreads();
  float a0=b1[j], a1=0.f, a2=0.f, a3=0.f;
  #pragma unroll
  for (int k=0; k<96; k+=4){
    a0 += st[k]*W1[j*97+k];     a1 += st[k+1]*W1[j*97+k+1];
    a2 += st[k+2]*W1[j*97+k+2]; a3 += st[k+3]*W1[j*97+k+3];
  }
  a0 += st[96]*W1[j*97+96];
  hm[j] = fmaxf((a0+a1)+(a2+a3), 0.0f);
  __syncthreads();
  if (j < 32){
    float c0_=b2[j], c1=0.f, c2=0.f, c3=0.f;
    #pragma unroll
    for (int k=0;k<64;k+=4){
      c0_ += hm[k]*W2[j*64+k];    c1 += hm[k+1]*W2[j*64+k+1];
      c2 += hm[k+2]*W2[j*64+k+2]; c3 += hm[k+3]*W2[j*64+k+3];
    }
    ctx[b*64+j] = (c0_+c1)+(c2+c3);
  }
}

// ---------------- GRU scan: 512 threads, quarter-split, 32 pinned f32/thread ----------------
// q = tid>>7 : q0 -> x (+bih), q1 -> rain_f, q2 -> rain_b, q3 -> h (+bhh)
__global__ __launch_bounds__(512,4) void k_gru(
    const float* __restrict__ x_comp, const float* __restrict__ rain_f,
    const float* __restrict__ rain_bw, const int* __restrict__ lengths,
    const float* __restrict__ Wih, const float* __restrict__ Whh,
    const float* __restrict__ bih, const float* __restrict__ bhh,
    float* __restrict__ ctx)
{
  const int b = blockIdx.x;
  const int tid = threadIdx.x;
  const int j = tid & 127;
  const int q = tid >> 7;
  const bool act = (j < 96);
  int len = lengths[b]; if (len > NT) len = NT;
  const float4 FZ4 = {0.f,0.f,0.f,0.f};
  const float4* W4 = (const float4*)((q < 3) ? (Wih + (size_t)j*96 + q*32)
                                             : (Whh + (size_t)j*32));
  float4 w0 = act ? W4[0] : FZ4;
  float4 w1 = act ? W4[1] : FZ4;
  float4 w2 = act ? W4[2] : FZ4;
  float4 w3 = act ? W4[3] : FZ4;
  float4 w4 = act ? W4[4] : FZ4;
  float4 w5 = act ? W4[5] : FZ4;
  float4 w6 = act ? W4[6] : FZ4;
  float4 w7 = act ? W4[7] : FZ4;
  PIN4(w0); PIN4(w1); PIN4(w2); PIN4(w3);
  PIN4(w4); PIN4(w5); PIN4(w6); PIN4(w7);
  float b0 = 0.f;
  if (act){ if (q == 0) b0 = bih[j]; else if (q == 3) b0 = bhh[j]; }
  __shared__ __align__(16) float h_lds[32];
  __shared__ __align__(16) float xrow[2][96];
  __shared__ float gpart[4][96];
  const float* xc = x_comp + (size_t)b*NT*NV;
  const float* rf = rain_f + (size_t)b*NT*NV;
  const float* rb = rain_bw + (size_t)b*NT*NV;
  if (tid < 32) h_lds[tid] = 0.0f;
  if (tid >= 128 && tid < 224){
    const int jj = tid - 128;
    xrow[0][jj] = (jj<32) ? xc[jj] : (jj<64 ? rf[jj-32] : rb[jj-64]);
  }
  __syncthreads();
  for (int t=0; t<len; ++t){
    const int cur = t & 1;
    float pf = 0.f;
    const bool dopf = (tid >= 128) && (tid < 224) && (t+1 < len);
    if (dopf){
      const int jj = tid - 128, tn = t+1;
      pf = (jj<32) ? xc[tn*NV+jj] : (jj<64 ? rf[tn*NV+jj-32] : rb[tn*NV+jj-64]);
    }
    if (act){
      const float* u = (q < 3) ? (&xrow[cur][0] + q*32) : &h_lds[0];
      float4 acc = {b0, 0.f, 0.f, 0.f};
      #define GSTEP(i) { const float4 uv = *(const float4*)(u + 4*i); \
        acc.x = fmaf(uv.x, w##i.x, acc.x); acc.y = fmaf(uv.y, w##i.y, acc.y); \
        acc.z = fmaf(uv.z, w##i.z, acc.z); acc.w = fmaf(uv.w, w##i.w, acc.w); }
      GSTEP(0) GSTEP(1) GSTEP(2) GSTEP(3) GSTEP(4) GSTEP(5) GSTEP(6) GSTEP(7)
      #undef GSTEP
      gpart[q][j] = hsum4_(acc);
    }
    if (dopf) xrow[cur^1][tid-128] = pf;
    __syncthreads();
    if (tid < 32){
      const float gr = gpart[0][tid]    + gpart[1][tid]    + gpart[2][tid]    + gpart[3][tid];
      const float gz = gpart[0][32+tid] + gpart[1][32+tid] + gpart[2][32+tid] + gpart[3][32+tid];
      const float gni = gpart[0][64+tid] + gpart[1][64+tid] + gpart[2][64+tid];
      const float gnh = gpart[3][64+tid];
      const float r = sigmoidf_(gr);
      const float z = sigmoidf_(gz);
      const float n = tanhf_(gni + r*gnh);
      h_lds[tid] = (1.0f - z)*n + z*h_lds[tid];
    }
    __syncthreads();
  }
  if (tid < 32) ctx[b*64 + 32 + tid] = h_lds[tid];
}

// ---------------- init: h0/c0, ctx-part of LSTM gates, hidden seeds ----------------
__global__ __launch_bounds__(256) void k_init(
    const float* __restrict__ ctx,
    const float* __restrict__ initW, const float* __restrict__ initb,
    const float* __restrict__ WihF, const float* __restrict__ bihF, const float* __restrict__ bhhF,
    const float* __restrict__ WihB, const float* __restrict__ bihB, const float* __restrict__ bhhB,
    float* __restrict__ h0, float* __restrict__ c0,
    float* __restrict__ cgF, float* __restrict__ cgB,
    float* __restrict__ hidden)
{
  const int b = blockIdx.x;
  const int j = threadIdx.x;
  __shared__ __align__(16) float cv[64];
  if (j < 64) cv[j] = ctx[b*64+j];
  __syncthreads();
  {
    float4 f = {bihF[j]+bhhF[j], 0.f, 0.f, 0.f};
    float4 g = {bihB[j]+bhhB[j], 0.f, 0.f, 0.f};
    #pragma unroll
    for (int q=0;q<16;q++){
      const float4 cvv = *(const float4*)&cv[4*q];
      const float4 wf = *(const float4*)(WihF + (size_t)j*128 + 64 + 4*q);
      const float4 wb = *(const float4*)(WihB + (size_t)j*128 + 64 + 4*q);
      f.x += cvv.x*wf.x; f.y += cvv.y*wf.y; f.z += cvv.z*wf.z; f.w += cvv.w*wf.w;
      g.x += cvv.x*wb.x; g.y += cvv.y*wb.y; g.z += cvv.z*wb.z; g.w += cvv.w*wb.w;
    }
    cgF[b*256+j] = hsum4_(f);
    cgB[b*256+j] = hsum4_(g);
  }
  if (j < 128){
    float4 a = {initb[j], 0.f, 0.f, 0.f};
    #pragma unroll
    for (int q=0;q<16;q++){
      const float4 cvv = *(const float4*)&cv[4*q];
      const float4 w  = *(const float4*)(initW + (size_t)j*64 + 4*q);
      a.x += cvv.x*w.x; a.y += cvv.y*w.y; a.z += cvv.z*w.z; a.w += cvv.w*w.w;
    }
    float hv = hsum4_(a);
    h0[b*128+j] = hv;
    c0[b*128+j] = tanhf_(hv);
    if (j < 64) hidden[(size_t)b*NT*128 + j] = hv;                                // fwd seed t=0
    else        hidden[(size_t)b*NT*128 + (size_t)(NT-1)*128 + 64 + (j-64)] = hv; // bwd seed t=T-1
  }
}

// ---------------- LSTM scans: 512 threads, half-split, f16-dot2, 32 pinned regs ----------------
// half = tid>>8 : half0 -> [x(32), mask(32)] via Wih cols 0..63 (+cg), half1 -> h via Whh
__global__ __launch_bounds__(512,4) void k_lstm(
    const float* __restrict__ x_comp, const float* __restrict__ masks,
    const float* __restrict__ WihF, const float* __restrict__ WhhF,
    const float* __restrict__ WihB, const float* __restrict__ WhhB,
    const float* __restrict__ cgF, const float* __restrict__ cgB,
    const float* __restrict__ h0, const float* __restrict__ c0,
    const int* __restrict__ lengths,
    float* __restrict__ hidden)
{
  const int b = blockIdx.x;
  const int dir = blockIdx.y;
  const int tid = threadIdx.x;
  const int j = tid & 255;
  const int half = tid >> 8;
  const float* Wih = dir ? WihB : WihF;
  const float* Whh = dir ? WhhB : WhhF;
  const float* Wsrc = half ? (Whh + (size_t)j*64) : (Wih + (size_t)j*128);
  // 64 weights -> 32 packed half2 in 32 VGPRs
  #define LW(k) float w##k = pack2_(Wsrc[2*(k)], Wsrc[2*(k)+1]); PINF(w##k);
  LW(0) LW(1) LW(2) LW(3) LW(4) LW(5) LW(6) LW(7)
  LW(8) LW(9) LW(10) LW(11) LW(12) LW(13) LW(14) LW(15)
  LW(16) LW(17) LW(18) LW(19) LW(20) LW(21) LW(22) LW(23)
  LW(24) LW(25) LW(26) LW(27) LW(28) LW(29) LW(30) LW(31)
  #undef LW
  const float cg0 = half ? 0.0f : (dir ? cgB : cgF)[b*256 + j];
  __shared__ __align__(16) float u2[2][32];   // packed x+mask pairs, double buffered
  __shared__ __align__(16) float hp[32];      // packed h pairs
  __shared__ float gpart[2][256];
  float c = 0.0f;
  const int len = lengths[b];
  int nsteps = NT-1;
  if (dir == 0){
    int e = len - 1; if (e < 0) e = 0;
    if (e < nsteps) nsteps = e;   // outputs past len are zeroed by padding mask
  }
  const float* xc = x_comp + (size_t)b*NT*NV;
  const float* mk = masks  + (size_t)b*NT*NV;
  float* hout = hidden + (size_t)b*NT*128 + dir*64;
  if (tid < 64){
    const float hv = h0[b*128 + dir*64 + tid];
    c              = c0[b*128 + dir*64 + tid];
    const float pr = __shfl_xor(hv, 1);
    if (!(tid & 1)) hp[tid>>1] = pack2_(hv, pr);
  }
  if (tid >= 448 && nsteps > 0){
    const int jj = tid - 448;
    const int t0 = dir ? NT-1 : 0;
    const float v = (jj<32) ? xc[t0*NV+jj] : mk[t0*NV+jj-32];
    const float pr = __shfl_xor(v, 1);
    if (!(jj & 1)) u2[0][jj>>1] = pack2_(v, pr);
  }
  __syncthreads();
  for (int s=0; s<nsteps; ++s){
    const int cur = s & 1;
    float pf = 0.f;
    const bool dopf = (tid >= 448) && (s+1 < nsteps);
    if (dopf){
      const int jj = tid - 448;
      const int tn = dir ? (NT-2-s) : (s+1);
      pf = (jj<32) ? xc[tn*NV+jj] : mk[tn*NV+jj-32];
    }
    const float* u = half ? &hp[0] : &u2[cur][0];
    const float4 U0 = *(const float4*)(u+0);
    const float4 U1 = *(const float4*)(u+4);
    const float4 U2 = *(const float4*)(u+8);
    const float4 U3 = *(const float4*)(u+12);
    const float4 U4 = *(const float4*)(u+16);
    const float4 U5 = *(const float4*)(u+20);
    const float4 U6 = *(const float4*)(u+24);
    const float4 U7 = *(const float4*)(u+28);
    float a0=cg0, a1=0.f, a2=0.f, a3=0.f;
    #define DQ(Un,i0,i1,i2,i3) \
      a0 = dot2f_(Un.x, w##i0, a0); a1 = dot2f_(Un.y, w##i1, a1); \
      a2 = dot2f_(Un.z, w##i2, a2); a3 = dot2f_(Un.w, w##i3, a3);
    DQ(U0,0,1,2,3)     DQ(U1,4,5,6,7)     DQ(U2,8,9,10,11)   DQ(U3,12,13,14,15)
    DQ(U4,16,17,18,19) DQ(U5,20,21,22,23) DQ(U6,24,25,26,27) DQ(U7,28,29,30,31)
    #undef DQ
    gpart[half][j] = (a0+a1)+(a2+a3);
    if (dopf){
      const int jj = tid - 448;
      const float pr = __shfl_xor(pf, 1);
      if (!(jj & 1)) u2[cur^1][jj>>1] = pack2_(pf, pr);
    }
    __syncthreads();
    if (tid < 64){
      const float gi = gpart[0][tid]     + gpart[1][tid];
      const float gf = gpart[0][64+tid]  + gpart[1][64+tid];
      const float gg = gpart[0][128+tid] + gpart[1][128+tid];
      const float go = gpart[0][192+tid] + gpart[1][192+tid];
      c = sigmoidf_(gf)*c + sigmoidf_(gi)*tanhf_(gg);
      const float hh = sigmoidf_(go)*tanhf_(c);
      const int t    = dir ? (NT-1-s) : s;
      const int outt = dir ? (t-1)    : (s+1);
      hout[(size_t)outt*128 + tid] = hh;
      const float pr = __shfl_xor(hh, 1);
      if (!(tid & 1)) hp[tid>>1] = pack2_(hh, pr);
    }
    __syncthreads();
  }
}

// ---------------- feature-regression path: 512 threads, 2 output rows per thread ----------------
__global__ __launch_bounds__(512,4) void k_feat(
    const float* __restrict__ x_comp,
    const float* __restrict__ feat_W, const float* __restrict__ feat_b,
    const float* __restrict__ nl1_W, const float* __restrict__ nl1_b,
    const float* __restrict__ nl2_W, const float* __restrict__ nl2_b,
    float* __restrict__ feat_imp)
{
  const int tid = threadIdx.x;
  const int lane = tid & 31;   // h-index (pass1), g-index (pass2)
  const int ig = tid >> 5;     // 0..15
  const int i0 = ig, i1 = ig + 16;
  const float4* A4 = (const float4*)(feat_W + ((size_t)(i0*32)+lane)*32);
  const float4* B4 = (const float4*)(feat_W + ((size_t)(i1*32)+lane)*32);
  #define LOADW(nm, P4, ii, cc) float4 nm = P4[cc]; \
    if (cc == ((ii)>>2)){ const int sub=(ii)&3; \
      if (sub==0) nm.x=0.f; else if (sub==1) nm.y=0.f; else if (sub==2) nm.z=0.f; else nm.w=0.f; } \
    PIN4(nm);
  LOADW(a0,A4,i0,0) LOADW(a1,A4,i0,1) LOADW(a2,A4,i0,2) LOADW(a3,A4,i0,3)
  LOADW(a4,A4,i0,4) LOADW(a5,A4,i0,5) LOADW(a6,A4,i0,6) LOADW(a7,A4,i0,7)
  LOADW(b0,B4,i1,0) LOADW(b1,B4,i1,1) LOADW(b2,B4,i1,2) LOADW(b3,B4,i1,3)
  LOADW(b4,B4,i1,4) LOADW(b5,B4,i1,5) LOADW(b6,B4,i1,6) LOADW(b7,B4,i1,7)
  #undef LOADW
  const float fb0 = feat_b[i0*32 + lane];
  const float fb1 = feat_b[i1*32 + lane];
  const float n1b = nl1_b[lane];
  const float n2w = nl2_W[lane];
  const float n2b = nl2_b[0];
  __shared__ __align__(16) float hid[32][36];
  __shared__ __align__(16) float nl1s[32][36];
  if (tid < 256){
    const int rrow = tid >> 3, c4 = (tid & 7) * 4;
    *(float4*)&nl1s[rrow][c4] = *(const float4*)(nl1_W + rrow*32 + c4);
  }
  __syncthreads();
  const int NP = NB*NT;
  for (int r = blockIdx.x; r < NP; r += gridDim.x){
    const float* xp = x_comp + (size_t)r*32;
    float4 acc0 = {fb0, 0.f, 0.f, 0.f};
    float4 acc1 = {fb1, 0.f, 0.f, 0.f};
    #define FST(i, an, bn) { const float4 xv = *(const float4*)(xp + 4*i); \
      acc0.x = fmaf(xv.x, an.x, acc0.x); acc0.y = fmaf(xv.y, an.y, acc0.y); \
      acc0.z = fmaf(xv.z, an.z, acc0.z); acc0.w = fmaf(xv.w, an.w, acc0.w); \
      acc1.x = fmaf(xv.x, bn.x, acc1.x); acc1.y = fmaf(xv.y, bn.y, acc1.y); \
      acc1.z = fmaf(xv.z, bn.z, acc1.z); acc1.w = fmaf(xv.w, bn.w, acc1.w); }
    FST(0,a0,b0) FST(1,a1,b1) FST(2,a2,b2) FST(3,a3,b3)
    FST(4,a4,b4) FST(5,a5,b5) FST(6,a6,b6) FST(7,a7,b7)
    #undef FST
    hid[i0][lane] = fmaxf(hsum4_(acc0), 0.0f);
    hid[i1][lane] = fmaxf(hsum4_(acc1), 0.0f);
    __syncthreads();
    float z0 = n1b, z1 = n1b;
    #pragma unroll
    for (int cc=0; cc<8; cc++){
      const float4 nn = *(const float4*)&nl1s[lane][4*cc];
      const float4 v0 = *(const float4*)&hid[i0][4*cc];
      const float4 v1 = *(const float4*)&hid[i1][4*cc];
      z0 += v0.x*nn.x + v0.y*nn.y + v0.z*nn.z + v0.w*nn.w;
      z1 += v1.x*nn.x + v1.y*nn.y + v1.z*nn.z + v1.w*nn.w;
    }
    float cr0 = fmaxf(z0, 0.f)*n2w;
    float cr1 = fmaxf(z1, 0.f)*n2w;
    #pragma unroll
    for (int off=16; off>0; off>>=1){
      cr0 += __shfl_xor(cr0, off, 32);
      cr1 += __shfl_xor(cr1, off, 32);
    }
    if (lane == 0){
      feat_imp[(size_t)r*32 + i0] = cr0 + n2b;
      feat_imp[(size_t)r*32 + i1] = cr1 + n2b;
    }
    __syncthreads();
  }
}

// ---------------- rnn_imp GEMM + fuse + final: 512 threads, half-split of 128-dot ----------------
__global__ __launch_bounds__(512,4) void k_final(
    const float* __restrict__ values, const float* __restrict__ masks,
    const float* __restrict__ feat_imp, const float* __restrict__ hidden,
    const float* __restrict__ rimp_W, const float* __restrict__ rimp_b,
    const float* __restrict__ fuse_W, const float* __restrict__ fuse_b,
    const int* __restrict__ lengths, float* __restrict__ out)
{
  const int tid = threadIdx.x;
  const int v = tid & 31;
  const int grp = (tid >> 5) & 7;
  const int half = tid >> 8;
  const float4 FZ4 = {0.f,0.f,0.f,0.f};
  const float4* W4 = (const float4*)(rimp_W + (size_t)v*128 + half*64);
  float4 w0 = W4[0],  w1 = W4[1],  w2 = W4[2],  w3 = W4[3];
  float4 w4 = W4[4],  w5 = W4[5],  w6 = W4[6],  w7 = W4[7];
  float4 w8 = W4[8],  w9 = W4[9],  w10 = W4[10], w11 = W4[11];
  float4 w12 = W4[12], w13 = W4[13], w14 = W4[14], w15 = W4[15];
  PIN4(w0); PIN4(w1); PIN4(w2); PIN4(w3); PIN4(w4); PIN4(w5); PIN4(w6); PIN4(w7);
  PIN4(w8); PIN4(w9); PIN4(w10); PIN4(w11); PIN4(w12); PIN4(w13); PIN4(w14); PIN4(w15);
  const float4* F4 = (const float4*)(fuse_W + (size_t)v*64 + 32);
  float fconst = 0.f;
  if (!half){
    fconst = fuse_b[v];
    #pragma unroll
    for (int q=0;q<8;q++) fconst += hsum4_(*(const float4*)(fuse_W + (size_t)v*64 + 4*q)); // gamma==1 part
  }
  const float rbias = rimp_b[v];
  __shared__ __align__(16) float hrow[8][128];
  __shared__ float rpart[8][32];
  __shared__ float bpart[8][32];
  const int NOCT = (NB*NT)/8;
  for (int oc = blockIdx.x; oc < NOCT; oc += gridDim.x){
    const size_t base = (size_t)oc*8;
    __syncthreads();
    if (tid < 256) ((float4*)hrow)[tid] = ((const float4*)(hidden + base*128))[tid];
    __syncthreads();
    const size_t r = base + grp;
    float4 a = {half ? 0.f : rbias, 0.f, 0.f, 0.f};
    const float* hb = &hrow[grp][half*64];
    #define RST(i) { const float4 hv = *(const float4*)(hb + 4*i); \
      a.x = fmaf(hv.x, w##i.x, a.x); a.y = fmaf(hv.y, w##i.y, a.y); \
      a.z = fmaf(hv.z, w##i.z, a.z); a.w = fmaf(hv.w, w##i.w, a.w); }
    RST(0) RST(1) RST(2) RST(3) RST(4) RST(5) RST(6) RST(7)
    RST(8) RST(9) RST(10) RST(11) RST(12) RST(13) RST(14) RST(15)
    #undef RST
    if (half){
      rpart[grp][v] = hsum4_(a);
      const float* mrow = masks + r*32;
      float4 acc4 = FZ4;
      #pragma unroll
      for (int q=0;q<8;q++){
        const float4 mv = *(const float4*)(mrow + 4*q);
        const float4 fv = F4[q];
        acc4.x = fmaf(mv.x, fv.x, acc4.x); acc4.y = fmaf(mv.y, fv.y, acc4.y);
        acc4.z = fmaf(mv.z, fv.z, acc4.z); acc4.w = fmaf(mv.w, fv.w, acc4.w);
      }
      bpart[grp][v] = hsum4_(acc4);
    }
    __syncthreads();
    if (!half){
      const int bb = (int)(r >> 9);   // T = 512
      const int t = (int)(r & 511);
      const int len = lengths[bb];
      const float rimp = hsum4_(a) + rpart[grp][v];
      const float beta = sigmoidf_(fconst + bpart[grp][v]);
      const float fi = feat_imp[r*32+v];
      const float m  = masks[r*32+v];
      const float val= values[r*32+v];
      const float fz = beta*fi + (1.0f-beta)*rimp;
      const float o = m*val + (1.0f-m)*fz;
      out[r*32+v] = (t < len) ? o : 0.0f;
    }
  }
}

extern "C" void kernel_launch(void* const* d_in, const int* in_sizes, int n_in,
                              void* d_out, int out_size, void* d_ws, size_t ws_size,
                              hipStream_t stream) {
  const float* values   = (const float*)d_in[0];
  const float* masks    = (const float*)d_in[1];
  const float* rain_f   = (const float*)d_in[2];
  const float* rain_b   = (const float*)d_in[3];
  const float* cmlp_W1  = (const float*)d_in[4];
  const float* cmlp_b1  = (const float*)d_in[5];
  const float* cmlp_W2  = (const float*)d_in[6];
  const float* cmlp_b2  = (const float*)d_in[7];
  const float* gru_Wih  = (const float*)d_in[8];
  const float* gru_Whh  = (const float*)d_in[9];
  const float* gru_bih  = (const float*)d_in[10];
  const float* gru_bhh  = (const float*)d_in[11];
  const float* init_W   = (const float*)d_in[12];
  const float* init_b   = (const float*)d_in[13];
  const float* lstmf_Wih= (const float*)d_in[14];
  const float* lstmf_Whh= (const float*)d_in[15];
  const float* lstmf_bih= (const float*)d_in[16];
  const float* lstmf_bhh= (const float*)d_in[17];
  const float* lstmb_Wih= (const float*)d_in[18];
  const float* lstmb_Whh= (const float*)d_in[19];
  const float* lstmb_bih= (const float*)d_in[20];
  const float* lstmb_bhh= (const float*)d_in[21];
  const float* rimp_W   = (const float*)d_in[22];
  const float* rimp_b   = (const float*)d_in[23];
  const float* feat_W   = (const float*)d_in[24];
  const float* feat_b   = (const float*)d_in[25];
  const float* nl1_W    = (const float*)d_in[26];
  const float* nl1_b    = (const float*)d_in[27];
  const float* nl2_W    = (const float*)d_in[28];
  const float* nl2_b    = (const float*)d_in[29];
  const float* fuse_W   = (const float*)d_in[30];
  const float* fuse_b   = (const float*)d_in[31];
  const int*   lengths  = (const int*)d_in[32];
  float* out = (float*)d_out;

  float* ws       = (float*)d_ws;
  float* x_comp   = ws;                                   // B*T*V
  float* stats    = x_comp + (size_t)NB*NT*NV;            // B*97
  float* ctx      = stats + NB*97;                        // B*64
  float* h0       = ctx + NB*64;                          // B*128
  float* c0      = h0 + NB*128;                           // B*128
  float* cgF      = c0 + NB*128;                          // B*256
  float* cgB      = cgF + NB*256;                         // B*256
  float* hidden   = cgB + NB*256;                         // B*T*128
  float* feat_imp = hidden + (size_t)NB*NT*128;           // B*T*V
  // total ~25.4M floats ~= 102 MB

  k_stats<<<NB, 256, 0, stream>>>(values, masks, lengths, x_comp, stats);
  k_feat<<<2048, 512, 0, stream>>>(x_comp, feat_W, feat_b, nl1_W, nl1_b, nl2_W, nl2_b, feat_imp);
  k_cmlp<<<NB, 64, 0, stream>>>(stats, cmlp_W1, cmlp_b1, cmlp_W2, cmlp_b2, ctx);
  k_gru<<<NB, 512, 0, stream>>>(x_comp, rain_f, rain_b, lengths, gru_Wih, gru_Whh, gru_bih, gru_bhh, ctx);
  k_init<<<NB, 256, 0, stream>>>(ctx, init_W, init_b,
                                 lstmf_Wih, lstmf_bih, lstmf_bhh,
                                 lstmb_Wih, lstmb_bih, lstmb_bhh,
                                 h0, c0, cgF, cgB, hidden);
  dim3 lgrid(NB, 2);
  k_lstm<<<lgrid, 512, 0, stream>>>(x_comp, masks,
                                    lstmf_Wih, lstmf_Whh, lstmb_Wih, lstmb_Whh,
                                    cgF, cgB, h0, c0, lengths, hidden);
  k_final<<<2048, 512, 0, stream>>>(values, masks, feat_imp, hidden,
                                    rimp_W, rimp_b, fuse_W, fuse_b, lengths, out);
}